// Round 7
// baseline (549.243 us; speedup 1.0000x reference)
//
#include <hip/hip_runtime.h>
#include <hip/hip_bf16.h>
#include <cstdint>
#include <cstddef>

#define TDIM 2048
#define NH 8

using f32x4 = __attribute__((ext_vector_type(4))) float;
using s16x8 = __attribute__((ext_vector_type(8))) short;

__device__ __forceinline__ float sigm(float x) { return 1.0f / (1.0f + __expf(-x)); }

#define GLDS(gp, lp)                                                          \
    __builtin_amdgcn_global_load_lds(                                         \
        (const __attribute__((address_space(1))) void*)(gp),                  \
        (__attribute__((address_space(3))) void*)(lp), 16, 0, 0)
#define GLDS4(gp, lp)                                                         \
    __builtin_amdgcn_global_load_lds(                                         \
        (const __attribute__((address_space(1))) void*)(gp),                  \
        (__attribute__((address_space(3))) void*)(lp), 4, 0, 0)

// DPP cross-lane adds (VALU pipe, no LDS).
template<int CTRL>
__device__ __forceinline__ float dpp_add(float x) {
    int p = __builtin_amdgcn_mov_dpp(__float_as_int(x), CTRL, 0xF, 0xF, true);
    return x + __int_as_float(p);
}
// sum over 16 lanes (low 4 bits of lane id): xor1, xor2, xor7, xor15
__device__ __forceinline__ float reduce16(float x) {
    x = dpp_add<0xB1>(x);   // quad_perm [1,0,3,2]
    x = dpp_add<0x4E>(x);   // quad_perm [2,3,0,1]
    x = dpp_add<0x141>(x);  // row_half_mirror (xor7)
    x = dpp_add<0x140>(x);  // row_mirror (xor15)
    return x;
}

// ---------------------------------------------------------------- pack kernels
__global__ __launch_bounds__(256) void pack_f32_bf16_kernel(
    const float* __restrict__ src, __hip_bfloat16* __restrict__ dst, int n4)
{
    int i = blockIdx.x * 256 + threadIdx.x;
    if (i >= n4) return;
    float4 v = *(const float4*)(src + (size_t)i * 4);
    size_t o = (size_t)i * 4;
    dst[o + 0] = __float2bfloat16(v.x);
    dst[o + 1] = __float2bfloat16(v.y);
    dst[o + 2] = __float2bfloat16(v.z);
    dst[o + 3] = __float2bfloat16(v.w);
}

__global__ __launch_bounds__(256) void pack_w_kernel(
    const float* __restrict__ Wq, const float* __restrict__ Wk,
    const float* __restrict__ Wv, const float* __restrict__ Wa,
    const float* __restrict__ Wb, const float* __restrict__ Wg,
    __hip_bfloat16* __restrict__ dst)
{
    int e = blockIdx.x * 256 + threadIdx.x;  // < 4224*1024
    int r = e >> 10, c = e & 1023;
    float vv;
    if      (r <  512) vv = Wq[(size_t)r * 1024 + c];
    else if (r < 1024) vv = Wk[(size_t)(r -  512) * 1024 + c];
    else if (r < 2048) vv = Wv[(size_t)(r - 1024) * 1024 + c];
    else if (r < 3072) vv = Wa[(size_t)(r - 2048) * 1024 + c];
    else if (r < 3080) vv = Wb[(size_t)(r - 3072) * 1024 + c];
    else if (r < 4104) vv = Wg[(size_t)(r - 3080) * 1024 + c];
    else               vv = 0.0f;
    dst[e] = __float2bfloat16(vv);
}

// ---------------------------------------------------------------- GEMM 1 (fused epilogue, coalesced stores)
__global__ __launch_bounds__(256) void gemm1_kernel(
    const __hip_bfloat16* __restrict__ A, const __hip_bfloat16* __restrict__ Bw,
    float* __restrict__ qraw, float* __restrict__ kraw, float* __restrict__ vraw,
    float* __restrict__ abuf, float* __restrict__ betab, float* __restrict__ gbuf,
    const float* __restrict__ ba, const float* __restrict__ bb)
{
    constexpr int Kd = 1024;
    __shared__ __attribute__((aligned(16))) __hip_bfloat16 At[128 * 32];
    __shared__ __attribute__((aligned(16))) __hip_bfloat16 Bt[128 * 32];
    __shared__ __attribute__((aligned(16))) float Ct[4][16 * 68];
    const int tid = threadIdx.x;
    const int mBase = blockIdx.x * 128;
    const int nBase = blockIdx.y * 128;
    const int wave = tid >> 6, lane = tid & 63;
    const int wm = (wave >> 1) * 64, wn = (wave & 1) * 64;
    const int quad = lane >> 4, l16 = lane & 15;

    f32x4 acc[4][4];
    for (int i = 0; i < 4; i++)
        for (int j = 0; j < 4; j++)
            for (int r = 0; r < 4; r++) acc[i][j][r] = 0.0f;

    const int srow = tid >> 2;
    const int skk = (tid & 3) * 8;
    const __hip_bfloat16* Ag = A + (size_t)(mBase + srow) * Kd + skk;
    const __hip_bfloat16* Bg = Bw + (size_t)(nBase + srow) * Kd + skk;
    __hip_bfloat16* Al = &At[srow * 32 + skk];
    __hip_bfloat16* Bl = &Bt[srow * 32 + skk];

    for (int k0 = 0; k0 < Kd; k0 += 32) {
        GLDS(Ag + k0, Al);
        GLDS(Ag + k0 + (size_t)64 * Kd, Al + 64 * 32);
        GLDS(Bg + k0, Bl);
        GLDS(Bg + k0 + (size_t)64 * Kd, Bl + 64 * 32);
        __syncthreads();
        s16x8 af[4], bfr[4];
#pragma unroll
        for (int i = 0; i < 4; i++)
            af[i] = *(const s16x8*)&At[(wm + i * 16 + l16) * 32 + quad * 8];
#pragma unroll
        for (int j = 0; j < 4; j++)
            bfr[j] = *(const s16x8*)&Bt[(wn + j * 16 + l16) * 32 + quad * 8];
#pragma unroll
        for (int i = 0; i < 4; i++)
#pragma unroll
            for (int j = 0; j < 4; j++)
                acc[i][j] = __builtin_amdgcn_mfma_f32_16x16x32_bf16(af[i], bfr[j], acc[i][j], 0, 0, 0);
        __syncthreads();
    }

    const int ncol = nBase + wn + l16 * 4;
    float* basep; size_t rstr; bool dosig = false; bool skip = false;
    float4 bias = make_float4(0.f, 0.f, 0.f, 0.f);
    if (ncol < 512)       { basep = qraw + ncol;          rstr = 512;  }
    else if (ncol < 1024) { basep = kraw + (ncol - 512);  rstr = 512;  }
    else if (ncol < 2048) { basep = vraw + (ncol - 1024); rstr = 1024; }
    else if (ncol < 3072) { basep = abuf + (ncol - 2048); rstr = 1024; dosig = true;
                            bias = *(const float4*)(ba + (ncol - 2048)); }
    else if (ncol < 3080) { basep = betab + (ncol - 3072); rstr = 8;   dosig = true;
                            bias = *(const float4*)(bb + (ncol - 3072)); }
    else if (ncol < 4104) { basep = gbuf + (ncol - 3080); rstr = 1024; dosig = true; }
    else                  { basep = gbuf; rstr = 0; skip = true; }

#pragma unroll
    for (int i = 0; i < 4; i++) {
#pragma unroll
        for (int j = 0; j < 4; j++)
#pragma unroll
            for (int r = 0; r < 4; r++)
                Ct[wave][(quad * 4 + r) * 68 + j * 16 + l16] = acc[i][j][r];
        __syncthreads();
#pragma unroll
        for (int p = 0; p < 4; p++) {
            int rr = p * 4 + quad;
            float4 val = *(const float4*)&Ct[wave][rr * 68 + l16 * 4];
            if (dosig) {
                val.x = sigm(val.x + bias.x);
                val.y = sigm(val.y + bias.y);
                val.z = sigm(val.z + bias.z);
                val.w = sigm(val.w + bias.w);
            }
            int m = mBase + wm + i * 16 + rr;
            if (!skip) *(float4*)(basep + (size_t)m * rstr) = val;
        }
        __syncthreads();
    }
}

// ---------------------------------------------------------------- GEMM 2 (plain, coalesced stores)
__global__ __launch_bounds__(256) void gemm2_kernel(
    const __hip_bfloat16* __restrict__ A, const __hip_bfloat16* __restrict__ Bw,
    float* __restrict__ out)
{
    constexpr int Kd = 1024;
    __shared__ __attribute__((aligned(16))) __hip_bfloat16 At[128 * 32];
    __shared__ __attribute__((aligned(16))) __hip_bfloat16 Bt[128 * 32];
    __shared__ __attribute__((aligned(16))) float Ct[4][16 * 68];
    const int tid = threadIdx.x;
    const int mBase = blockIdx.x * 128;
    const int nBase = blockIdx.y * 128;
    const int wave = tid >> 6, lane = tid & 63;
    const int wm = (wave >> 1) * 64, wn = (wave & 1) * 64;
    const int quad = lane >> 4, l16 = lane & 15;

    f32x4 acc[4][4];
    for (int i = 0; i < 4; i++)
        for (int j = 0; j < 4; j++)
            for (int r = 0; r < 4; r++) acc[i][j][r] = 0.0f;

    const int srow = tid >> 2;
    const int skk = (tid & 3) * 8;
    const __hip_bfloat16* Ag = A + (size_t)(mBase + srow) * Kd + skk;
    const __hip_bfloat16* Bg = Bw + (size_t)(nBase + srow) * Kd + skk;
    __hip_bfloat16* Al = &At[srow * 32 + skk];
    __hip_bfloat16* Bl = &Bt[srow * 32 + skk];

    for (int k0 = 0; k0 < Kd; k0 += 32) {
        GLDS(Ag + k0, Al);
        GLDS(Ag + k0 + (size_t)64 * Kd, Al + 64 * 32);
        GLDS(Bg + k0, Bl);
        GLDS(Bg + k0 + (size_t)64 * Kd, Bl + 64 * 32);
        __syncthreads();
        s16x8 af[4], bfr[4];
#pragma unroll
        for (int i = 0; i < 4; i++)
            af[i] = *(const s16x8*)&At[(wm + i * 16 + l16) * 32 + quad * 8];
#pragma unroll
        for (int j = 0; j < 4; j++)
            bfr[j] = *(const s16x8*)&Bt[(wn + j * 16 + l16) * 32 + quad * 8];
#pragma unroll
        for (int i = 0; i < 4; i++)
#pragma unroll
            for (int j = 0; j < 4; j++)
                acc[i][j] = __builtin_amdgcn_mfma_f32_16x16x32_bf16(af[i], bfr[j], acc[i][j], 0, 0, 0);
        __syncthreads();
    }

    const int ncol = nBase + wn + l16 * 4;
    float* basep = out + ncol;
#pragma unroll
    for (int i = 0; i < 4; i++) {
#pragma unroll
        for (int j = 0; j < 4; j++)
#pragma unroll
            for (int r = 0; r < 4; r++)
                Ct[wave][(quad * 4 + r) * 68 + j * 16 + l16] = acc[i][j][r];
        __syncthreads();
#pragma unroll
        for (int p = 0; p < 4; p++) {
            int rr = p * 4 + quad;
            float4 val = *(const float4*)&Ct[wave][rr * 68 + l16 * 4];
            int m = mBase + wm + i * 16 + rr;
            *(float4*)(basep + (size_t)m * 1024) = val;
        }
        __syncthreads();
    }
}

// ---------------------------------------------------------------- fused depthwise causal conv (K=4) + SiLU
// v12: 4 timesteps per thread -> 7 loads + 4 stores per 4 outputs.
__global__ __launch_bounds__(256) void conv_silu_fused_kernel(
    const float* __restrict__ qraw, const float* __restrict__ kraw,
    const float* __restrict__ vraw,
    const float* __restrict__ qw, const float* __restrict__ qb,
    const float* __restrict__ kw, const float* __restrict__ kb,
    const float* __restrict__ vw, const float* __restrict__ vb,
    float* __restrict__ qcb, float* __restrict__ kcb, float* __restrict__ vcb)
{
    int e = blockIdx.x * 256 + threadIdx.x;   // [0, 2048*2048): (b,T/4) x 2048 chans
    int c = e & 2047;
    int bt4 = e >> 11;                        // b*512 + t/4
    int t0 = (bt4 & 511) * 4;
    int bb_ = bt4 >> 9;
    const float* src; float* dst; const float* w4; const float* bi;
    int C, cc; float scale = 1.0f;
    if (c < 512)       { src = qraw; dst = qcb; w4 = qw; bi = qb; C = 512;  cc = c; }
    else if (c < 1024) { src = kraw; dst = kcb; w4 = kw; bi = kb; C = 512;  cc = c - 512; scale = 0.125f; }
    else               { src = vraw; dst = vcb; w4 = vw; bi = vb; C = 1024; cc = c - 1024; }
    const float* wc = w4 + (size_t)cc * 4;
    const float w0 = wc[0], w1 = wc[1], w2 = wc[2], w3 = wc[3];
    const float bs = bi[cc];
    const float* s = src + ((size_t)bb_ * TDIM + t0) * C + cc;
    float x0, x1, x2;
    if (t0 == 0) { x0 = 0.f; x1 = 0.f; x2 = 0.f; }
    else { x0 = s[-3 * C]; x1 = s[-2 * C]; x2 = s[-C]; }
    const float x3 = s[0], x4 = s[C], x5 = s[2 * C], x6 = s[3 * C];
    float* d = dst + ((size_t)bb_ * TDIM + t0) * C + cc;
    float y;
    y = fmaf(w0, x0, fmaf(w1, x1, fmaf(w2, x2, fmaf(w3, x3, bs))));
    d[0] = y * sigm(y) * scale;
    y = fmaf(w0, x1, fmaf(w1, x2, fmaf(w2, x3, fmaf(w3, x4, bs))));
    d[C] = y * sigm(y) * scale;
    y = fmaf(w0, x2, fmaf(w1, x3, fmaf(w2, x4, fmaf(w3, x5, bs))));
    d[2 * C] = y * sigm(y) * scale;
    y = fmaf(w0, x3, fmaf(w1, x4, fmaf(w2, x5, fmaf(w3, x6, bs))));
    d[3 * C] = y * sigm(y) * scale;
}

// ---------------------------------------------------------------- gated delta-rule scan v13
// v12 base (3 LDS reads/step, lgkm<=12) + two serial-latency fixes:
// 1) o-reduces DEFERRED: oacc[t] keeps per-lane partials during the chunk;
//    all 32 reduce16 trees run at chunk end (independent -> fully interleaved,
//    issue-bound, zero per-step stall). Same instruction count as before.
// 2) r-chain PAIR-EXPANDED (v9's proven algebra, r-side only): per step-pair
//    the 3 reduces u1=k1^T S, u2=k2^T S, g21=k2^T k1 are mutually independent
//    (one tree latency per pair), then c2 = B2*(A1*u2 - c1*g21 - V2) without a
//    second serial tree. S and o updates stay in exact sequential form.
#define CH 32
#define NCHUNK (TDIM / CH)

#define SCAN_STAGE_KQ(BUF, T0) do {                                           \
    _Pragma("unroll") for (int j = 0; j < 8; j++) {                           \
        int flat = j * 64 + lane;                                             \
        int tt = flat >> 4, c4 = (flat & 15) * 4;                             \
        GLDS(kc + kqB + (size_t)((T0) + tt) * 512 + c4, &kL[BUF][j * 256]);   \
        GLDS(qc + kqB + (size_t)((T0) + tt) * 512 + c4, &qL[BUF][j * 256]);   \
    }                                                                         \
} while (0)

// Load operands for step TT of buffer BUF into prefetch slot SL. 3 LDS reads.
#define LOADOPS(BUF, TT, SL) do {                                             \
    kR[SL] = *(const float4*)&kL[BUF][(TT) * 64 + ks * 4];                    \
    qR[SL] = *(const float4*)&qL[BUF][(TT) * 64 + ks * 4];                    \
    vabR[SL] = *(const float4*)&vabL[BUF][((TT) * 4 + vi) * 4];               \
} while (0)

// Compute steps TA, TA+1 from prefetch slots SLA, SLB. Branch-free.
// o-partials are NOT reduced here (deferred to chunk end).
#define CPAIR(SLA, SLB, TA) do {                                              \
    const float4 k1 = kR[SLA], q1 = qR[SLA];                                  \
    const float4 k2 = kR[SLB], q2 = qR[SLB];                                  \
    const float V1 = vabR[SLA].x, A1 = vabR[SLA].y, B1 = vabR[SLA].z;         \
    const float V2 = vabR[SLB].x, A2 = vabR[SLB].y, B2 = vabR[SLB].z;         \
    float u1 = k1.x * S0, u2 = k2.x * S0, g21 = k2.x * k1.x;                  \
    u1 = fmaf(k1.y, S1, u1); u2 = fmaf(k2.y, S1, u2);                         \
    g21 = fmaf(k2.y, k1.y, g21);                                              \
    u1 = fmaf(k1.z, S2, u1); u2 = fmaf(k2.z, S2, u2);                         \
    g21 = fmaf(k2.z, k1.z, g21);                                              \
    u1 = fmaf(k1.w, S3, u1); u2 = fmaf(k2.w, S3, u2);                         \
    g21 = fmaf(k2.w, k1.w, g21);                                              \
    u1 = reduce16(u1); u2 = reduce16(u2); g21 = reduce16(g21);                \
    const float c1 = B1 * (u1 - V1);                                          \
    S0 = fmaf(-c1, k1.x, A1 * S0); float o0 = q1.x * S0;                      \
    S1 = fmaf(-c1, k1.y, A1 * S1); float o1 = q1.y * S1;                      \
    S2 = fmaf(-c1, k1.z, A1 * S2); o0 = fmaf(q1.z, S2, o0);                   \
    S3 = fmaf(-c1, k1.w, A1 * S3); o1 = fmaf(q1.w, S3, o1);                   \
    oacc[TA] = o0 + o1;                                                       \
    const float u2p = fmaf(A1, u2, -(c1 * g21));                              \
    const float c2 = B2 * (u2p - V2);                                         \
    S0 = fmaf(-c2, k2.x, A2 * S0); float p0 = q2.x * S0;                      \
    S1 = fmaf(-c2, k2.y, A2 * S1); float p1 = q2.y * S1;                      \
    S2 = fmaf(-c2, k2.z, A2 * S2); p0 = fmaf(q2.z, S2, p0);                   \
    S3 = fmaf(-c2, k2.w, A2 * S3); p1 = fmaf(q2.w, S3, p1);                   \
    oacc[(TA) + 1] = p0 + p1;                                                 \
} while (0)

__global__ __launch_bounds__(64) void scan_kernel(
    const float* __restrict__ qc, const float* __restrict__ kc,
    const float* __restrict__ vc, const float* __restrict__ ab,
    const float* __restrict__ betab, float* __restrict__ ob)
{
    __shared__ __attribute__((aligned(16))) float kL[2][CH * 64];
    __shared__ __attribute__((aligned(16))) float qL[2][CH * 64];
    __shared__ __attribute__((aligned(16))) float vabL[2][CH * 4 * 4]; // [t][vi]={v,a,be,0}
    __shared__ __attribute__((aligned(16))) float oL[4 * CH];   // [vi][t]

    const int bid = blockIdx.x;
    const int bh = bid & 31, vg = bid >> 5;   // XCD-affinity: same bh -> same bid%8
    const int h = bh & 7, b = bh >> 3;
    const int lane = threadIdx.x;
    const int ks = lane & 15, vi = lane >> 4;

    const size_t kqB = (size_t)b * TDIM * 512 + (size_t)h * 64;
    const size_t vaB = (size_t)b * TDIM * 1024 + (size_t)h * 128 + (size_t)vg * 4;
    const size_t beB = (size_t)b * TDIM * 8 + h;

    // reg-staging lane -> (t, vi) mapping for vab (2 pairs per lane)
    const int t0p = lane >> 2, c0p = lane & 3;   // pairs 0..63  (t 0..15)
    const int t1p = 16 + t0p;                    // pairs 64..127 (t 16..31)

    float S0 = 0, S1 = 0, S2 = 0, S3 = 0;
    float4 kR[4], qR[4], vabR[4];
    float oacc[CH];

    // ---- prologue: stage chunk 0
    SCAN_STAGE_KQ(0, 0);
    {
        float v0 = vc[vaB + (size_t)t0p * 1024 + c0p];
        float a0 = ab[vaB + (size_t)t0p * 1024 + c0p];
        float e0 = betab[beB + (size_t)t0p * 8];
        float v1 = vc[vaB + (size_t)t1p * 1024 + c0p];
        float a1 = ab[vaB + (size_t)t1p * 1024 + c0p];
        float e1 = betab[beB + (size_t)t1p * 8];
        *(float4*)&vabL[0][lane * 4] = make_float4(v0, a0, e0, 0.f);
        *(float4*)&vabL[0][(64 + lane) * 4] = make_float4(v1, a1, e1, 0.f);
    }
    __syncthreads();
    LOADOPS(0, 0, 0); LOADOPS(0, 1, 1); LOADOPS(0, 2, 2); LOADOPS(0, 3, 3);

    for (int chk = 0; chk < NCHUNK; chk++) {
        const int buf = chk & 1;
        const int nb = buf ^ 1;
        const int tn = (chk + 1 < NCHUNK) ? (chk + 1) * CH : 0;
        SCAN_STAGE_KQ(nb, tn);
        // issue next-chunk vab global loads now; latency hides under 32 steps
        const float nv0 = vc[vaB + (size_t)(tn + t0p) * 1024 + c0p];
        const float na0 = ab[vaB + (size_t)(tn + t0p) * 1024 + c0p];
        const float ne0 = betab[beB + (size_t)(tn + t0p) * 8];
        const float nv1 = vc[vaB + (size_t)(tn + t1p) * 1024 + c0p];
        const float na1 = ab[vaB + (size_t)(tn + t1p) * 1024 + c0p];
        const float ne1 = betab[beB + (size_t)(tn + t1p) * 8];
#pragma unroll
        for (int t = 0; t < CH; t += 2) {
            CPAIR(t & 3, (t + 1) & 3, t);
            if (t + 4 < CH) {
                LOADOPS(buf, t + 4, t & 3);
                LOADOPS(buf, t + 5, (t + 1) & 3);
            }
        }
        // deferred o-reduction: 32 independent trees, fully interleaved
#pragma unroll
        for (int j = 0; j < CH; j++) oacc[j] = reduce16(oacc[j]);
        // write staged vab for next chunk (before the barrier)
        *(float4*)&vabL[nb][lane * 4] = make_float4(nv0, na0, ne0, 0.f);
        *(float4*)&vabL[nb][(64 + lane) * 4] = make_float4(nv1, na1, ne1, 0.f);
        // one exec-masked region per chunk: dump oacc -> oL (row-per-vi layout)
        if (ks == 0) {
#pragma unroll
            for (int j = 0; j < 8; j++) {
                float4 o4 = make_float4(oacc[j * 4], oacc[j * 4 + 1],
                                        oacc[j * 4 + 2], oacc[j * 4 + 3]);
                *(float4*)&oL[vi * CH + j * 4] = o4;
            }
        }
        __syncthreads();  // drains next-chunk staging (vmcnt) + oL/vabL visibility
        if (lane < CH) {
            float4 ov = make_float4(oL[0 * CH + lane], oL[1 * CH + lane],
                                    oL[2 * CH + lane], oL[3 * CH + lane]);
            *(float4*)(ob + vaB + (size_t)(chk * CH + lane) * 1024) = ov;
        }
        LOADOPS(nb, 0, 0); LOADOPS(nb, 1, 1); LOADOPS(nb, 2, 2); LOADOPS(nb, 3, 3);
    }
}

// ---------------------------------------------------------------- LayerNorm(DV=128) + gate -> bf16
__global__ __launch_bounds__(256) void ln_gate_kernel(
    const float* __restrict__ ob, const float* __restrict__ g,
    const float* __restrict__ lnw, const float* __restrict__ lnb,
    __hip_bfloat16* __restrict__ opr)
{
    int row = blockIdx.x * 4 + (threadIdx.x >> 6);
    int lane = threadIdx.x & 63;
    size_t base = (size_t)row * 128 + lane * 2;
    float2 xv = *(const float2*)(ob + base);
    float s = xv.x + xv.y;
#pragma unroll
    for (int m = 1; m <= 32; m <<= 1) s += __shfl_xor(s, m);
    float mean = s * (1.0f / 128.0f);
    float d0 = xv.x - mean, d1 = xv.y - mean;
    float vs = d0 * d0 + d1 * d1;
#pragma unroll
    for (int m = 1; m <= 32; m <<= 1) vs += __shfl_xor(vs, m);
    float rstd = rsqrtf(vs * (1.0f / 128.0f) + 1e-5f);
    float2 gv = *(const float2*)(g + base);
    float w0 = lnw[lane * 2], w1 = lnw[lane * 2 + 1];
    float b0 = lnb[lane * 2], b1 = lnb[lane * 2 + 1];
    opr[base] = __float2bfloat16((d0 * rstd * w0 + b0) * gv.x);
    opr[base + 1] = __float2bfloat16((d1 * rstd * w1 + b1) * gv.y);
}

// ---------------------------------------------------------------- launch
extern "C" void kernel_launch(void* const* d_in, const int* in_sizes, int n_in,
                              void* d_out, int out_size, void* d_ws, size_t ws_size,
                              hipStream_t stream)
{
    const float* x    = (const float*)d_in[0];
    const float* Wq   = (const float*)d_in[1];
    const float* Wk   = (const float*)d_in[2];
    const float* Wv   = (const float*)d_in[3];
    const float* Wa   = (const float*)d_in[4];
    const float* ba   = (const float*)d_in[5];
    const float* Wb   = (const float*)d_in[6];
    const float* bb   = (const float*)d_in[7];
    const float* Wg   = (const float*)d_in[8];
    const float* Wo   = (const float*)d_in[9];
    const float* qc_w = (const float*)d_in[10];
    const float* qc_b = (const float*)d_in[11];
    const float* kc_w = (const float*)d_in[12];
    const float* kc_b = (const float*)d_in[13];
    const float* vc_w = (const float*)d_in[14];
    const float* vc_b = (const float*)d_in[15];
    const float* ln_w = (const float*)d_in[16];
    const float* ln_b = (const float*)d_in[17];
    float* out = (float*)d_out;

    char* W = (char*)d_ws;
    __hip_bfloat16* xbf  = (__hip_bfloat16*)(W + 0);            // 16777216
    __hip_bfloat16* wcat = (__hip_bfloat16*)(W + 16777216);     // 8650752
    __hip_bfloat16* wobf = (__hip_bfloat16*)(W + 25427968);     // 2097152
    float* qraw  = (float*)(W + 27525120);                      // 16777216
    float* kraw  = (float*)(W + 44302336);                      // 16777216
    float* vraw  = (float*)(W + 61079552);                      // 33554432
    float* abuf  = (float*)(W + 94633984);                      // 33554432
    float* betab = (float*)(W + 128188416);                     // 262144
    float* gbuf  = (float*)(W + 128450560);                     // 33554432
    float* kcb   = (float*)(W + 162004992);                     // 16777216
    float* vcb   = (float*)(W + 178782208);                     // 33554432
    float* qcb   = (float*)xbf;                 // reuse: xbf dead after gemm1
    float* obuf  = (float*)qraw;                // reuse: qraw+kraw dead after convs
    __hip_bfloat16* opr = (__hip_bfloat16*)vraw;// reuse: vraw dead after conv-v

    pack_f32_bf16_kernel<<<8192, 256, 0, stream>>>(x, xbf, 2097152);
    pack_w_kernel<<<16896, 256, 0, stream>>>(Wq, Wk, Wv, Wa, Wb, Wg, wcat);
    pack_f32_bf16_kernel<<<1024, 256, 0, stream>>>(Wo, wobf, 262144);
    gemm1_kernel<<<dim3(64, 33), 256, 0, stream>>>(xbf, wcat, qraw, kraw, vraw,
                                                   abuf, betab, gbuf, ba, bb);
    conv_silu_fused_kernel<<<16384, 256, 0, stream>>>(
        qraw, kraw, vraw, qc_w, qc_b, kc_w, kc_b, vc_w, vc_b, qcb, kcb, vcb);
    scan_kernel<<<1024, 64, 0, stream>>>(qcb, kcb, vcb, abuf, betab, obuf);
    ln_gate_kernel<<<16384, 256, 0, stream>>>(obuf, gbuf, ln_w, ln_b, opr);
    gemm2_kernel<<<dim3(64, 8), 256, 0, stream>>>(opr, wobf, out);
}

// Round 8
// 500.170 us; speedup vs baseline: 1.0981x; 1.0981x over previous
//
#include <hip/hip_runtime.h>
#include <hip/hip_bf16.h>
#include <cstdint>
#include <cstddef>

#define TDIM 2048
#define NH 8

using f32x4 = __attribute__((ext_vector_type(4))) float;
using s16x8 = __attribute__((ext_vector_type(8))) short;

__device__ __forceinline__ float sigm(float x) { return 1.0f / (1.0f + __expf(-x)); }

#define GLDS(gp, lp)                                                          \
    __builtin_amdgcn_global_load_lds(                                         \
        (const __attribute__((address_space(1))) void*)(gp),                  \
        (__attribute__((address_space(3))) void*)(lp), 16, 0, 0)
#define GLDS4(gp, lp)                                                         \
    __builtin_amdgcn_global_load_lds(                                         \
        (const __attribute__((address_space(1))) void*)(gp),                  \
        (__attribute__((address_space(3))) void*)(lp), 4, 0, 0)

// DPP cross-lane adds (VALU pipe, no LDS).
template<int CTRL>
__device__ __forceinline__ float dpp_add(float x) {
    int p = __builtin_amdgcn_mov_dpp(__float_as_int(x), CTRL, 0xF, 0xF, true);
    return x + __int_as_float(p);
}
// sum over 16 lanes (low 4 bits of lane id): xor1, xor2, xor7, xor15
__device__ __forceinline__ float reduce16(float x) {
    x = dpp_add<0xB1>(x);   // quad_perm [1,0,3,2]
    x = dpp_add<0x4E>(x);   // quad_perm [2,3,0,1]
    x = dpp_add<0x141>(x);  // row_half_mirror (xor7)
    x = dpp_add<0x140>(x);  // row_mirror (xor15)
    return x;
}

// ---------------------------------------------------------------- pack kernels
__global__ __launch_bounds__(256) void pack_f32_bf16_kernel(
    const float* __restrict__ src, __hip_bfloat16* __restrict__ dst, int n4)
{
    int i = blockIdx.x * 256 + threadIdx.x;
    if (i >= n4) return;
    float4 v = *(const float4*)(src + (size_t)i * 4);
    size_t o = (size_t)i * 4;
    dst[o + 0] = __float2bfloat16(v.x);
    dst[o + 1] = __float2bfloat16(v.y);
    dst[o + 2] = __float2bfloat16(v.z);
    dst[o + 3] = __float2bfloat16(v.w);
}

__global__ __launch_bounds__(256) void pack_w_kernel(
    const float* __restrict__ Wq, const float* __restrict__ Wk,
    const float* __restrict__ Wv, const float* __restrict__ Wa,
    const float* __restrict__ Wb, const float* __restrict__ Wg,
    __hip_bfloat16* __restrict__ dst)
{
    int e = blockIdx.x * 256 + threadIdx.x;  // < 4224*1024
    int r = e >> 10, c = e & 1023;
    float vv;
    if      (r <  512) vv = Wq[(size_t)r * 1024 + c];
    else if (r < 1024) vv = Wk[(size_t)(r -  512) * 1024 + c];
    else if (r < 2048) vv = Wv[(size_t)(r - 1024) * 1024 + c];
    else if (r < 3072) vv = Wa[(size_t)(r - 2048) * 1024 + c];
    else if (r < 3080) vv = Wb[(size_t)(r - 3072) * 1024 + c];
    else if (r < 4104) vv = Wg[(size_t)(r - 3080) * 1024 + c];
    else               vv = 0.0f;
    dst[e] = __float2bfloat16(vv);
}

// ---------------------------------------------------------------- GEMM 1 (2-phase dbuf staging, fused epilogue)
#define G1STAGE(BUF, K0) do {                                                 \
    GLDS(Ag + (K0), &At[BUF][srow * 32 + skk]);                               \
    GLDS(Ag + (K0) + (size_t)64 * Kd, &At[BUF][(64 + srow) * 32 + skk]);      \
    GLDS(Bg + (K0), &Bt[BUF][srow * 32 + skk]);                               \
    GLDS(Bg + (K0) + (size_t)64 * Kd, &Bt[BUF][(64 + srow) * 32 + skk]);      \
} while (0)

__global__ __launch_bounds__(256) void gemm1_kernel(
    const __hip_bfloat16* __restrict__ A, const __hip_bfloat16* __restrict__ Bw,
    float* __restrict__ qraw, float* __restrict__ kraw, float* __restrict__ vraw,
    float* __restrict__ abuf, float* __restrict__ betab, float* __restrict__ gbuf,
    const float* __restrict__ ba, const float* __restrict__ bb)
{
    constexpr int Kd = 1024;
    __shared__ __attribute__((aligned(16))) __hip_bfloat16 At[2][128 * 32];
    __shared__ __attribute__((aligned(16))) __hip_bfloat16 Bt[2][128 * 32];
    __shared__ __attribute__((aligned(16))) float Ct[4][16 * 68];
    const int tid = threadIdx.x;
    const int mBase = blockIdx.x * 128;
    const int nBase = blockIdx.y * 128;
    const int wave = tid >> 6, lane = tid & 63;
    const int wm = (wave >> 1) * 64, wn = (wave & 1) * 64;
    const int quad = lane >> 4, l16 = lane & 15;

    f32x4 acc[4][4];
    for (int i = 0; i < 4; i++)
        for (int j = 0; j < 4; j++)
            for (int r = 0; r < 4; r++) acc[i][j][r] = 0.0f;

    const int srow = tid >> 2;
    const int skk = (tid & 3) * 8;
    const __hip_bfloat16* Ag = A + (size_t)(mBase + srow) * Kd + skk;
    const __hip_bfloat16* Bg = Bw + (size_t)(nBase + srow) * Kd + skk;

    // prologue: stage K-tile 0 into buf 0; barrier drains it
    G1STAGE(0, 0);
    __syncthreads();
    for (int k0 = 0; k0 < Kd; k0 += 32) {
        const int cb = (k0 >> 5) & 1;
        if (k0 + 32 < Kd) G1STAGE(cb ^ 1, k0 + 32);   // prefetch next tile
        s16x8 af[4], bfr[4];
#pragma unroll
        for (int i = 0; i < 4; i++)
            af[i] = *(const s16x8*)&At[cb][(wm + i * 16 + l16) * 32 + quad * 8];
#pragma unroll
        for (int j = 0; j < 4; j++)
            bfr[j] = *(const s16x8*)&Bt[cb][(wn + j * 16 + l16) * 32 + quad * 8];
#pragma unroll
        for (int i = 0; i < 4; i++)
#pragma unroll
            for (int j = 0; j < 4; j++)
                acc[i][j] = __builtin_amdgcn_mfma_f32_16x16x32_bf16(af[i], bfr[j], acc[i][j], 0, 0, 0);
        __syncthreads();   // implicit vmcnt(0): prefetch landed; all reads of cb done
    }

    const int ncol = nBase + wn + l16 * 4;
    float* basep; size_t rstr; bool dosig = false; bool skip = false;
    float4 bias = make_float4(0.f, 0.f, 0.f, 0.f);
    if (ncol < 512)       { basep = qraw + ncol;          rstr = 512;  }
    else if (ncol < 1024) { basep = kraw + (ncol - 512);  rstr = 512;  }
    else if (ncol < 2048) { basep = vraw + (ncol - 1024); rstr = 1024; }
    else if (ncol < 3072) { basep = abuf + (ncol - 2048); rstr = 1024; dosig = true;
                            bias = *(const float4*)(ba + (ncol - 2048)); }
    else if (ncol < 3080) { basep = betab + (ncol - 3072); rstr = 8;   dosig = true;
                            bias = *(const float4*)(bb + (ncol - 3072)); }
    else if (ncol < 4104) { basep = gbuf + (ncol - 3080); rstr = 1024; dosig = true; }
    else                  { basep = gbuf; rstr = 0; skip = true; }

#pragma unroll
    for (int i = 0; i < 4; i++) {
#pragma unroll
        for (int j = 0; j < 4; j++)
#pragma unroll
            for (int r = 0; r < 4; r++)
                Ct[wave][(quad * 4 + r) * 68 + j * 16 + l16] = acc[i][j][r];
        __syncthreads();
#pragma unroll
        for (int p = 0; p < 4; p++) {
            int rr = p * 4 + quad;
            float4 val = *(const float4*)&Ct[wave][rr * 68 + l16 * 4];
            if (dosig) {
                val.x = sigm(val.x + bias.x);
                val.y = sigm(val.y + bias.y);
                val.z = sigm(val.z + bias.z);
                val.w = sigm(val.w + bias.w);
            }
            int m = mBase + wm + i * 16 + rr;
            if (!skip) *(float4*)(basep + (size_t)m * rstr) = val;
        }
        __syncthreads();
    }
}

// ---------------------------------------------------------------- GEMM 2 (2-phase dbuf staging)
__global__ __launch_bounds__(256) void gemm2_kernel(
    const __hip_bfloat16* __restrict__ A, const __hip_bfloat16* __restrict__ Bw,
    float* __restrict__ out)
{
    constexpr int Kd = 1024;
    __shared__ __attribute__((aligned(16))) __hip_bfloat16 At[2][128 * 32];
    __shared__ __attribute__((aligned(16))) __hip_bfloat16 Bt[2][128 * 32];
    __shared__ __attribute__((aligned(16))) float Ct[4][16 * 68];
    const int tid = threadIdx.x;
    const int mBase = blockIdx.x * 128;
    const int nBase = blockIdx.y * 128;
    const int wave = tid >> 6, lane = tid & 63;
    const int wm = (wave >> 1) * 64, wn = (wave & 1) * 64;
    const int quad = lane >> 4, l16 = lane & 15;

    f32x4 acc[4][4];
    for (int i = 0; i < 4; i++)
        for (int j = 0; j < 4; j++)
            for (int r = 0; r < 4; r++) acc[i][j][r] = 0.0f;

    const int srow = tid >> 2;
    const int skk = (tid & 3) * 8;
    const __hip_bfloat16* Ag = A + (size_t)(mBase + srow) * Kd + skk;
    const __hip_bfloat16* Bg = Bw + (size_t)(nBase + srow) * Kd + skk;

    G1STAGE(0, 0);
    __syncthreads();
    for (int k0 = 0; k0 < Kd; k0 += 32) {
        const int cb = (k0 >> 5) & 1;
        if (k0 + 32 < Kd) G1STAGE(cb ^ 1, k0 + 32);
        s16x8 af[4], bfr[4];
#pragma unroll
        for (int i = 0; i < 4; i++)
            af[i] = *(const s16x8*)&At[cb][(wm + i * 16 + l16) * 32 + quad * 8];
#pragma unroll
        for (int j = 0; j < 4; j++)
            bfr[j] = *(const s16x8*)&Bt[cb][(wn + j * 16 + l16) * 32 + quad * 8];
#pragma unroll
        for (int i = 0; i < 4; i++)
#pragma unroll
            for (int j = 0; j < 4; j++)
                acc[i][j] = __builtin_amdgcn_mfma_f32_16x16x32_bf16(af[i], bfr[j], acc[i][j], 0, 0, 0);
        __syncthreads();
    }

    const int ncol = nBase + wn + l16 * 4;
    float* basep = out + ncol;
#pragma unroll
    for (int i = 0; i < 4; i++) {
#pragma unroll
        for (int j = 0; j < 4; j++)
#pragma unroll
            for (int r = 0; r < 4; r++)
                Ct[wave][(quad * 4 + r) * 68 + j * 16 + l16] = acc[i][j][r];
        __syncthreads();
#pragma unroll
        for (int p = 0; p < 4; p++) {
            int rr = p * 4 + quad;
            float4 val = *(const float4*)&Ct[wave][rr * 68 + l16 * 4];
            int m = mBase + wm + i * 16 + rr;
            *(float4*)(basep + (size_t)m * 1024) = val;
        }
        __syncthreads();
    }
}

// ---------------------------------------------------------------- fused depthwise causal conv (K=4) + SiLU
// 4 timesteps per thread -> 7 loads + 4 stores per 4 outputs.
__global__ __launch_bounds__(256) void conv_silu_fused_kernel(
    const float* __restrict__ qraw, const float* __restrict__ kraw,
    const float* __restrict__ vraw,
    const float* __restrict__ qw, const float* __restrict__ qb,
    const float* __restrict__ kw, const float* __restrict__ kb,
    const float* __restrict__ vw, const float* __restrict__ vb,
    float* __restrict__ qcb, float* __restrict__ kcb, float* __restrict__ vcb)
{
    int e = blockIdx.x * 256 + threadIdx.x;   // [0, 2048*2048): (b,T/4) x 2048 chans
    int c = e & 2047;
    int bt4 = e >> 11;                        // b*512 + t/4
    int t0 = (bt4 & 511) * 4;
    int bb_ = bt4 >> 9;
    const float* src; float* dst; const float* w4; const float* bi;
    int C, cc; float scale = 1.0f;
    if (c < 512)       { src = qraw; dst = qcb; w4 = qw; bi = qb; C = 512;  cc = c; }
    else if (c < 1024) { src = kraw; dst = kcb; w4 = kw; bi = kb; C = 512;  cc = c - 512; scale = 0.125f; }
    else               { src = vraw; dst = vcb; w4 = vw; bi = vb; C = 1024; cc = c - 1024; }
    const float* wc = w4 + (size_t)cc * 4;
    const float w0 = wc[0], w1 = wc[1], w2 = wc[2], w3 = wc[3];
    const float bs = bi[cc];
    const float* s = src + ((size_t)bb_ * TDIM + t0) * C + cc;
    float x0, x1, x2;
    if (t0 == 0) { x0 = 0.f; x1 = 0.f; x2 = 0.f; }
    else { x0 = s[-3 * C]; x1 = s[-2 * C]; x2 = s[-C]; }
    const float x3 = s[0], x4 = s[C], x5 = s[2 * C], x6 = s[3 * C];
    float* d = dst + ((size_t)bb_ * TDIM + t0) * C + cc;
    float y;
    y = fmaf(w0, x0, fmaf(w1, x1, fmaf(w2, x2, fmaf(w3, x3, bs))));
    d[0] = y * sigm(y) * scale;
    y = fmaf(w0, x1, fmaf(w1, x2, fmaf(w2, x3, fmaf(w3, x4, bs))));
    d[C] = y * sigm(y) * scale;
    y = fmaf(w0, x2, fmaf(w1, x3, fmaf(w2, x4, fmaf(w3, x5, bs))));
    d[2 * C] = y * sigm(y) * scale;
    y = fmaf(w0, x3, fmaf(w1, x4, fmaf(w2, x5, fmaf(w3, x6, bs))));
    d[3 * C] = y * sigm(y) * scale;
}

// ---------------------------------------------------------------- gated delta-rule scan v12 (frozen best: 227 us)
// 1024 blocks x 64 threads (1 wave each). 3 LDS reads/step (k b128, q b128,
// v/a/beta packed float4) x 4-deep prefetch -> steady-state lgkm = 12 <= 15
// so the counted lgkmcnt wait is expressible and ds_read latency stays off
// the chain. v/a/beta staged per chunk via register burst + ds_write_b128.
#define CH 32
#define NCHUNK (TDIM / CH)

#define SCAN_STAGE_KQ(BUF, T0) do {                                           \
    _Pragma("unroll") for (int j = 0; j < 8; j++) {                           \
        int flat = j * 64 + lane;                                             \
        int tt = flat >> 4, c4 = (flat & 15) * 4;                             \
        GLDS(kc + kqB + (size_t)((T0) + tt) * 512 + c4, &kL[BUF][j * 256]);   \
        GLDS(qc + kqB + (size_t)((T0) + tt) * 512 + c4, &qL[BUF][j * 256]);   \
    }                                                                         \
} while (0)

// Load operands for step TT of buffer BUF into prefetch slot SL. 3 LDS reads.
#define LOADOPS(BUF, TT, SL) do {                                             \
    kR[SL] = *(const float4*)&kL[BUF][(TT) * 64 + ks * 4];                    \
    qR[SL] = *(const float4*)&qL[BUF][(TT) * 64 + ks * 4];                    \
    vabR[SL] = *(const float4*)&vabL[BUF][((TT) * 4 + vi) * 4];               \
} while (0)

// Compute step TT from prefetch slot SL. Branch-free.
#define CSTEP(SL, TT) do {                                                    \
    const float4 kk = kR[SL];                                                 \
    const float4 qq = qR[SL];                                                 \
    const float VV = vabR[SL].x, AA = vabR[SL].y, BB = vabR[SL].z;            \
    float as0 = AA * S0, as1 = AA * S1, as2 = AA * S2, as3 = AA * S3;         \
    float nbv = VV * (-BB);                                                   \
    float r0 = kk.x * S0, r1 = kk.y * S1;                                     \
    r0 = fmaf(kk.z, S2, r0); r1 = fmaf(kk.w, S3, r1);                         \
    float rr = reduce16(r0 + r1);                                             \
    float cc = fmaf(BB, rr, nbv);                                             \
    S0 = fmaf(-cc, kk.x, as0); float o0 = qq.x * S0;                          \
    S1 = fmaf(-cc, kk.y, as1); float o1 = qq.y * S1;                          \
    S2 = fmaf(-cc, kk.z, as2); o0 = fmaf(qq.z, S2, o0);                       \
    S3 = fmaf(-cc, kk.w, as3); o1 = fmaf(qq.w, S3, o1);                       \
    oacc[TT] = reduce16(o0 + o1);                                             \
} while (0)

__global__ __launch_bounds__(64) void scan_kernel(
    const float* __restrict__ qc, const float* __restrict__ kc,
    const float* __restrict__ vc, const float* __restrict__ ab,
    const float* __restrict__ betab, float* __restrict__ ob)
{
    __shared__ __attribute__((aligned(16))) float kL[2][CH * 64];
    __shared__ __attribute__((aligned(16))) float qL[2][CH * 64];
    __shared__ __attribute__((aligned(16))) float vabL[2][CH * 4 * 4]; // [t][vi]={v,a,be,0}
    __shared__ __attribute__((aligned(16))) float oL[4 * CH];   // [vi][t]

    const int bid = blockIdx.x;
    const int bh = bid & 31, vg = bid >> 5;   // XCD-affinity: same bh -> same bid%8
    const int h = bh & 7, b = bh >> 3;
    const int lane = threadIdx.x;
    const int ks = lane & 15, vi = lane >> 4;

    const size_t kqB = (size_t)b * TDIM * 512 + (size_t)h * 64;
    const size_t vaB = (size_t)b * TDIM * 1024 + (size_t)h * 128 + (size_t)vg * 4;
    const size_t beB = (size_t)b * TDIM * 8 + h;

    // reg-staging lane -> (t, vi) mapping for vab (2 pairs per lane)
    const int t0p = lane >> 2, c0p = lane & 3;   // pairs 0..63  (t 0..15)
    const int t1p = 16 + t0p;                    // pairs 64..127 (t 16..31)

    float S0 = 0, S1 = 0, S2 = 0, S3 = 0;
    float4 kR[4], qR[4], vabR[4];
    float oacc[CH];

    // ---- prologue: stage chunk 0
    SCAN_STAGE_KQ(0, 0);
    {
        float v0 = vc[vaB + (size_t)t0p * 1024 + c0p];
        float a0 = ab[vaB + (size_t)t0p * 1024 + c0p];
        float e0 = betab[beB + (size_t)t0p * 8];
        float v1 = vc[vaB + (size_t)t1p * 1024 + c0p];
        float a1 = ab[vaB + (size_t)t1p * 1024 + c0p];
        float e1 = betab[beB + (size_t)t1p * 8];
        *(float4*)&vabL[0][lane * 4] = make_float4(v0, a0, e0, 0.f);
        *(float4*)&vabL[0][(64 + lane) * 4] = make_float4(v1, a1, e1, 0.f);
    }
    __syncthreads();
    LOADOPS(0, 0, 0); LOADOPS(0, 1, 1); LOADOPS(0, 2, 2); LOADOPS(0, 3, 3);

    for (int chk = 0; chk < NCHUNK; chk++) {
        const int buf = chk & 1;
        const int nb = buf ^ 1;
        const int tn = (chk + 1 < NCHUNK) ? (chk + 1) * CH : 0;
        SCAN_STAGE_KQ(nb, tn);
        // issue next-chunk vab global loads now; latency hides under 32 steps
        const float nv0 = vc[vaB + (size_t)(tn + t0p) * 1024 + c0p];
        const float na0 = ab[vaB + (size_t)(tn + t0p) * 1024 + c0p];
        const float ne0 = betab[beB + (size_t)(tn + t0p) * 8];
        const float nv1 = vc[vaB + (size_t)(tn + t1p) * 1024 + c0p];
        const float na1 = ab[vaB + (size_t)(tn + t1p) * 1024 + c0p];
        const float ne1 = betab[beB + (size_t)(tn + t1p) * 8];
#pragma unroll
        for (int t = 0; t < CH; t++) {
            CSTEP(t & 3, t);
            if (t + 4 < CH) LOADOPS(buf, t + 4, t & 3);
        }
        // write staged vab for next chunk (before the barrier)
        *(float4*)&vabL[nb][lane * 4] = make_float4(nv0, na0, ne0, 0.f);
        *(float4*)&vabL[nb][(64 + lane) * 4] = make_float4(nv1, na1, ne1, 0.f);
        // one exec-masked region per chunk: dump oacc -> oL (row-per-vi layout)
        if (ks == 0) {
#pragma unroll
            for (int j = 0; j < 8; j++) {
                float4 o4 = make_float4(oacc[j * 4], oacc[j * 4 + 1],
                                        oacc[j * 4 + 2], oacc[j * 4 + 3]);
                *(float4*)&oL[vi * CH + j * 4] = o4;
            }
        }
        __syncthreads();  // drains next-chunk staging (vmcnt) + oL/vabL visibility
        if (lane < CH) {
            float4 ov = make_float4(oL[0 * CH + lane], oL[1 * CH + lane],
                                    oL[2 * CH + lane], oL[3 * CH + lane]);
            *(float4*)(ob + vaB + (size_t)(chk * CH + lane) * 1024) = ov;
        }
        LOADOPS(nb, 0, 0); LOADOPS(nb, 1, 1); LOADOPS(nb, 2, 2); LOADOPS(nb, 3, 3);
    }
}

// ---------------------------------------------------------------- LayerNorm(DV=128) + gate -> bf16
__global__ __launch_bounds__(256) void ln_gate_kernel(
    const float* __restrict__ ob, const float* __restrict__ g,
    const float* __restrict__ lnw, const float* __restrict__ lnb,
    __hip_bfloat16* __restrict__ opr)
{
    int row = blockIdx.x * 4 + (threadIdx.x >> 6);
    int lane = threadIdx.x & 63;
    size_t base = (size_t)row * 128 + lane * 2;
    float2 xv = *(const float2*)(ob + base);
    float s = xv.x + xv.y;
#pragma unroll
    for (int m = 1; m <= 32; m <<= 1) s += __shfl_xor(s, m);
    float mean = s * (1.0f / 128.0f);
    float d0 = xv.x - mean, d1 = xv.y - mean;
    float vs = d0 * d0 + d1 * d1;
#pragma unroll
    for (int m = 1; m <= 32; m <<= 1) vs += __shfl_xor(vs, m);
    float rstd = rsqrtf(vs * (1.0f / 128.0f) + 1e-5f);
    float2 gv = *(const float2*)(g + base);
    float w0 = lnw[lane * 2], w1 = lnw[lane * 2 + 1];
    float b0 = lnb[lane * 2], b1 = lnb[lane * 2 + 1];
    opr[base] = __float2bfloat16((d0 * rstd * w0 + b0) * gv.x);
    opr[base + 1] = __float2bfloat16((d1 * rstd * w1 + b1) * gv.y);
}

// ---------------------------------------------------------------- launch
extern "C" void kernel_launch(void* const* d_in, const int* in_sizes, int n_in,
                              void* d_out, int out_size, void* d_ws, size_t ws_size,
                              hipStream_t stream)
{
    const float* x    = (const float*)d_in[0];
    const float* Wq   = (const float*)d_in[1];
    const float* Wk   = (const float*)d_in[2];
    const float* Wv   = (const float*)d_in[3];
    const float* Wa   = (const float*)d_in[4];
    const float* ba   = (const float*)d_in[5];
    const float* Wb   = (const float*)d_in[6];
    const float* bb   = (const float*)d_in[7];
    const float* Wg   = (const float*)d_in[8];
    const float* Wo   = (const float*)d_in[9];
    const float* qc_w = (const float*)d_in[10];
    const float* qc_b = (const float*)d_in[11];
    const float* kc_w = (const float*)d_in[12];
    const float* kc_b = (const float*)d_in[13];
    const float* vc_w = (const float*)d_in[14];
    const float* vc_b = (const float*)d_in[15];
    const float* ln_w = (const float*)d_in[16];
    const float* ln_b = (const float*)d_in[17];
    float* out = (float*)d_out;

    char* W = (char*)d_ws;
    __hip_bfloat16* xbf  = (__hip_bfloat16*)(W + 0);            // 16777216
    __hip_bfloat16* wcat = (__hip_bfloat16*)(W + 16777216);     // 8650752
    __hip_bfloat16* wobf = (__hip_bfloat16*)(W + 25427968);     // 2097152
    float* qraw  = (float*)(W + 27525120);                      // 16777216
    float* kraw  = (float*)(W + 44302336);                      // 16777216
    float* vraw  = (float*)(W + 61079552);                      // 33554432
    float* abuf  = (float*)(W + 94633984);                      // 33554432
    float* betab = (float*)(W + 128188416);                     // 262144
    float* gbuf  = (float*)(W + 128450560);                     // 33554432
    float* kcb   = (float*)(W + 162004992);                     // 16777216
    float* vcb   = (float*)(W + 178782208);                     // 33554432
    float* qcb   = (float*)xbf;                 // reuse: xbf dead after gemm1
    float* obuf  = (float*)qraw;                // reuse: qraw+kraw dead after convs
    __hip_bfloat16* opr = (__hip_bfloat16*)vraw;// reuse: vraw dead after conv-v

    pack_f32_bf16_kernel<<<8192, 256, 0, stream>>>(x, xbf, 2097152);
    pack_w_kernel<<<16896, 256, 0, stream>>>(Wq, Wk, Wv, Wa, Wb, Wg, wcat);
    pack_f32_bf16_kernel<<<1024, 256, 0, stream>>>(Wo, wobf, 262144);
    gemm1_kernel<<<dim3(64, 33), 256, 0, stream>>>(xbf, wcat, qraw, kraw, vraw,
                                                   abuf, betab, gbuf, ba, bb);
    conv_silu_fused_kernel<<<16384, 256, 0, stream>>>(
        qraw, kraw, vraw, qc_w, qc_b, kc_w, kc_b, vc_w, vc_b, qcb, kcb, vcb);
    scan_kernel<<<1024, 64, 0, stream>>>(qcb, kcb, vcb, abuf, betab, obuf);
    ln_gate_kernel<<<16384, 256, 0, stream>>>(obuf, gbuf, ln_w, ln_b, opr);
    gemm2_kernel<<<dim3(64, 8), 256, 0, stream>>>(opr, wobf, out);
}